// Round 1
// baseline (287.513 us; speedup 1.0000x reference)
//
#include <hip/hip_runtime.h>

// MultiRegionalFusionModule: out[b,t,s,f] = tgt[b,t,s,f] +
//   sum_k softmax_k(corr[tci[b,t], ri[k]]) * rv[b,k,f,s]
// B=8 T=32 S=512 F=128 K=64 N=200, all fp32 (indices int32).
//
// Memory-bound: ideal traffic = 64 (tgt) + 128 (rv) + 64 (out) MiB ~= 42 us.
// Block = (b, s-tile of 64, f-tile of 16); 4 waves split T (8 t each).
// rv loads are s-fast coalesced; LDS tile transposes to f-fast stores.

constexpr int Bn = 8, Tn = 32, Sn = 512, Fn = 128, Kn = 64, Nn = 200;
constexpr int S_TILE = 64;   // lane = s offset
constexpr int F_TILE = 16;   // f per block
// grid = Bn * (Sn/S_TILE) * (Fn/F_TILE) = 8*8*8 = 512 blocks of 256 threads

__global__ __launch_bounds__(256, 2)
void mrf_kernel(const float* __restrict__ tgt,
                const float* __restrict__ rv,
                const float* __restrict__ corr,
                const int*   __restrict__ tci,
                const int*   __restrict__ ri,
                float*       __restrict__ out)
{
    // attnT[k][t], t-dim padded 32->36 so float4 reads stay 16B-aligned and
    // prologue writes (stride 36 floats) are only mildly conflicted (one-off).
    __shared__ float attnT[Kn][36];
    // per-wave epilogue transpose tile, pad 17 -> 2-way conflicts only (free)
    __shared__ float etile[4][S_TILE][17];

    const int tid  = threadIdx.x;
    const int w    = tid >> 6;    // wave 0..3 -> t chunk
    const int lane = tid & 63;    // s offset in tile

    const int bid = blockIdx.x;
    const int b  = bid >> 6;
    const int sb = (bid >> 3) & 7;
    const int fb = bid & 7;
    const int s0 = sb * S_TILE;
    const int f0 = fb * F_TILE;

    // ---- prologue: softmax over K for this b's 32 target rows ----
    // lane = k; wave w handles t = w, w+4, ..., w+28
    {
        const int rik = ri[lane];                 // regional col index
        #pragma unroll
        for (int j = 0; j < 8; ++j) {
            const int t   = w + 4 * j;
            const int row = tci[b * Tn + t];      // target country row
            float c = corr[row * Nn + rik];
            float m = c;
            #pragma unroll
            for (int off = 32; off; off >>= 1)
                m = fmaxf(m, __shfl_xor(m, off));
            float e = __expf(c - m);
            float s = e;
            #pragma unroll
            for (int off = 32; off; off >>= 1)
                s += __shfl_xor(s, off);
            attnT[lane][t] = e / s;
        }
    }
    __syncthreads();

    // ---- main loop: acc[f][t] over k ----
    const int t0 = w * 8;
    float acc[F_TILE][8];
    #pragma unroll
    for (int j = 0; j < F_TILE; ++j)
        #pragma unroll
        for (int tt = 0; tt < 8; ++tt)
            acc[j][tt] = 0.0f;

    // rv index: ((b*K + k)*F + f)*S + s
    const float* rvp = rv + ((size_t)b * Kn * Fn + f0) * (size_t)Sn + s0 + lane;

    for (int k = 0; k < Kn; ++k) {
        const float4 a0 = *(const float4*)&attnT[k][t0];
        const float4 a1 = *(const float4*)&attnT[k][t0 + 4];
        const float* p  = rvp + (size_t)k * Fn * Sn;
        float v[F_TILE];
        #pragma unroll
        for (int j = 0; j < F_TILE; ++j)
            v[j] = p[(size_t)j * Sn];             // coalesced over lane=s
        #pragma unroll
        for (int j = 0; j < F_TILE; ++j) {
            acc[j][0] = fmaf(v[j], a0.x, acc[j][0]);
            acc[j][1] = fmaf(v[j], a0.y, acc[j][1]);
            acc[j][2] = fmaf(v[j], a0.z, acc[j][2]);
            acc[j][3] = fmaf(v[j], a0.w, acc[j][3]);
            acc[j][4] = fmaf(v[j], a1.x, acc[j][4]);
            acc[j][5] = fmaf(v[j], a1.y, acc[j][5]);
            acc[j][6] = fmaf(v[j], a1.z, acc[j][6]);
            acc[j][7] = fmaf(v[j], a1.w, acc[j][7]);
        }
    }

    // ---- epilogue: LDS transpose (s-fast regs -> f-fast stores) + residual ----
    const int fg = lane & 15;     // f offset for read-back/stores
    const int sg = lane >> 4;     // s group
    for (int tt = 0; tt < 8; ++tt) {
        const int t = t0 + tt;
        #pragma unroll
        for (int j = 0; j < F_TILE; ++j)
            etile[w][lane][j] = acc[j][tt];       // lane = s, write its 16 f
        __syncthreads();
        const size_t rowbase = (((size_t)(b * Tn + t)) * Sn + s0) * Fn + f0;
        const float* tr   = tgt + rowbase;
        float*       outr = out + rowbase;
        #pragma unroll
        for (int si = 0; si < 16; ++si) {
            const int ss  = si * 4 + sg;
            const int off = ss * Fn + fg;         // f-fast: full 64B segments
            outr[off] = tr[off] + etile[w][ss][fg];
        }
        __syncthreads();
    }
}

extern "C" void kernel_launch(void* const* d_in, const int* in_sizes, int n_in,
                              void* d_out, int out_size, void* d_ws, size_t ws_size,
                              hipStream_t stream)
{
    const float* tgt  = (const float*)d_in[0];   // [B,T,S,F]
    const float* rv   = (const float*)d_in[1];   // [B,K,F,S]
    const float* corr = (const float*)d_in[2];   // [N,N]
    const int*   tci  = (const int*)d_in[3];     // [B,T]
    const int*   ri   = (const int*)d_in[4];     // [K]
    float*       out  = (float*)d_out;           // [B,T,S,F]

    dim3 grid(Bn * (Sn / S_TILE) * (Fn / F_TILE));  // 512
    dim3 block(256);
    hipLaunchKernelGGL(mrf_kernel, grid, block, 0, stream,
                       tgt, rv, corr, tci, ri, out);
}

// Round 2
// 283.615 us; speedup vs baseline: 1.0137x; 1.0137x over previous
//
#include <hip/hip_runtime.h>

// MultiRegionalFusionModule: out[b,t,s,f] = tgt[b,t,s,f] +
//   sum_k softmax_k(corr[tci[b,t], ri[k]]) * rv[b,k,f,s]
// B=8 T=32 S=512 F=128 K=64 N=200, fp32 (indices int32 from harness).
//
// R1 was latency-bound: grid 512 = 2 blocks/CU -> 19.9% occupancy, HBM 21%.
// R2: S_TILE 64->32, grid 1024 = 4 blocks/CU; acc 128->64 VGPR so
// __launch_bounds__(256,4) holds 16 waves/CU. F_TILE stays 16 so epilogue
// stores remain 64B-contiguous per f-row (smaller F_TILE would split 64B
// write segments across blocks/XCDs -> HBM write amplification).

constexpr int Bn = 8, Tn = 32, Sn = 512, Fn = 128, Kn = 64, Nn = 200;
constexpr int S_TILE = 32;   // 64 lanes = 2 f-rows x 32 s per load instr
constexpr int F_TILE = 16;
// grid = Bn * (Sn/S_TILE) * (Fn/F_TILE) = 8*16*8 = 1024 blocks of 256

__global__ __launch_bounds__(256, 4)
void mrf_kernel(const float* __restrict__ tgt,
                const float* __restrict__ rv,
                const float* __restrict__ corr,
                const int*   __restrict__ tci,
                const int*   __restrict__ ri,
                float*       __restrict__ out)
{
    // attnT rows padded to 36 floats (144B) -> float4 reads stay 16B-aligned
    __shared__ float attnT[Kn][36];
    // epilogue transpose tile per wave, 2 t's per round; pad 18 -> worst
    // 2-way bank aliasing on both write and read (free per m136)
    __shared__ float etile[4][2][S_TILE][18];

    const int tid  = threadIdx.x;
    const int w    = tid >> 6;    // wave -> t chunk of 8
    const int lane = tid & 63;

    const int bid = blockIdx.x;
    const int b  = bid >> 7;
    const int sb = (bid >> 3) & 15;
    const int fb = bid & 7;
    const int s0 = sb * S_TILE;
    const int f0 = fb * F_TILE;

    // ---- prologue: softmax over K (lane = k) for this b's 32 t rows ----
    {
        const int rik = ri[lane];
        #pragma unroll
        for (int j = 0; j < 8; ++j) {
            const int t   = w + 4 * j;
            const int row = tci[b * Tn + t];
            float c = corr[row * Nn + rik];
            float m = c;
            #pragma unroll
            for (int off = 32; off; off >>= 1)
                m = fmaxf(m, __shfl_xor(m, off));
            float e = __expf(c - m);
            float s = e;
            #pragma unroll
            for (int off = 32; off; off >>= 1)
                s += __shfl_xor(s, off);
            attnT[lane][t] = e / s;
        }
    }
    __syncthreads();

    // ---- main loop over k: acc[f pair-row][t] ----
    const int t0 = w * 8;
    const int s_ = lane & 31;     // s offset
    const int fh = lane >> 5;     // f parity: lane 0-31 even f-row, 32-63 odd

    float acc[8][8];
    #pragma unroll
    for (int j = 0; j < 8; ++j)
        #pragma unroll
        for (int tt = 0; tt < 8; ++tt)
            acc[j][tt] = 0.0f;

    // rv index: ((b*K + k)*F + f)*S + s ; this lane covers f = f0+2j+fh
    const float* rvp = rv + ((size_t)(b * Kn) * Fn + f0 + fh) * (size_t)Sn
                          + s0 + s_;

    #pragma unroll 2
    for (int k = 0; k < Kn; ++k) {
        const float4 a0 = *(const float4*)&attnT[k][t0];
        const float4 a1 = *(const float4*)&attnT[k][t0 + 4];
        const float* p  = rvp + (size_t)k * Fn * Sn;
        float v[8];
        #pragma unroll
        for (int j = 0; j < 8; ++j)
            v[j] = p[(size_t)(2 * j) * Sn];   // 2 x 128B segments per instr
        #pragma unroll
        for (int j = 0; j < 8; ++j) {
            acc[j][0] = fmaf(v[j], a0.x, acc[j][0]);
            acc[j][1] = fmaf(v[j], a0.y, acc[j][1]);
            acc[j][2] = fmaf(v[j], a0.z, acc[j][2]);
            acc[j][3] = fmaf(v[j], a0.w, acc[j][3]);
            acc[j][4] = fmaf(v[j], a1.x, acc[j][4]);
            acc[j][5] = fmaf(v[j], a1.y, acc[j][5]);
            acc[j][6] = fmaf(v[j], a1.z, acc[j][6]);
            acc[j][7] = fmaf(v[j], a1.w, acc[j][7]);
        }
    }

    // ---- epilogue: LDS transpose (s-fast regs -> f-fast stores) + residual
    const int fg = lane & 15;     // f offset for read-back/stores
    const int sg = lane >> 4;     // s group (4 rows per instr -> 4x64B segs)
    for (int r = 0; r < 4; ++r) {
        #pragma unroll
        for (int tt2 = 0; tt2 < 2; ++tt2) {
            const int tt = r * 2 + tt2;
            #pragma unroll
            for (int j = 0; j < 8; ++j)
                etile[w][tt2][s_][2 * j + fh] = acc[j][tt];
        }
        __syncthreads();
        #pragma unroll
        for (int tt2 = 0; tt2 < 2; ++tt2) {
            const int t = t0 + r * 2 + tt2;
            const size_t rowbase = (((size_t)(b * Tn + t)) * Sn + s0) * Fn + f0;
            const float* tr   = tgt + rowbase;
            float*       outr = out + rowbase;
            #pragma unroll
            for (int si = 0; si < 8; ++si) {
                const int ss  = si * 4 + sg;
                const int off = ss * Fn + fg;
                outr[off] = tr[off] + etile[w][tt2][ss][fg];
            }
        }
        __syncthreads();
    }
}

extern "C" void kernel_launch(void* const* d_in, const int* in_sizes, int n_in,
                              void* d_out, int out_size, void* d_ws, size_t ws_size,
                              hipStream_t stream)
{
    const float* tgt  = (const float*)d_in[0];   // [B,T,S,F]
    const float* rv   = (const float*)d_in[1];   // [B,K,F,S]
    const float* corr = (const float*)d_in[2];   // [N,N]
    const int*   tci  = (const int*)d_in[3];     // [B,T]
    const int*   ri   = (const int*)d_in[4];     // [K]
    float*       out  = (float*)d_out;           // [B,T,S,F]

    dim3 grid(Bn * (Sn / S_TILE) * (Fn / F_TILE));  // 1024
    dim3 block(256);
    hipLaunchKernelGGL(mrf_kernel, grid, block, 0, stream,
                       tgt, rv, corr, tci, ri, out);
}